// Round 4
// baseline (1758.672 us; speedup 1.0000x reference)
//
#include <hip/hip_runtime.h>
#include <cstdint>
#include <cstddef>

#define TSTEPS 1000
#define NB     256
#define NR     200
#define NI     10
#define ALPHA_F     0.1f
#define NOISE_STD_F 0.01f
#define ETA_STRIDE  (NB * NR)          // 51200 floats per timestep
#define ETA_FLOATS  ((size_t)TSTEPS * NB * NR)

// ---------------- JAX threefry2x32-20, key = (0, 42) --------------------
__device__ __forceinline__ uint32_t rotl32(uint32_t v, uint32_t d) {
  return (v << d) | (v >> (32u - d));
}

__device__ __forceinline__ uint32_t threefry_bits(uint32_t c1) {
  const uint32_t ks0 = 0u;
  const uint32_t ks1 = 42u;
  const uint32_t ks2 = 0x1BD11BDAu ^ ks0 ^ ks1;
  uint32_t x0 = ks0;
  uint32_t x1 = c1 + ks1;
#define TFR(r) { x0 += x1; x1 = rotl32(x1, (r)); x1 ^= x0; }
  TFR(13) TFR(15) TFR(26) TFR(6)   x0 += ks1; x1 += ks2 + 1u;
  TFR(17) TFR(29) TFR(16) TFR(24)  x0 += ks2; x1 += ks0 + 2u;
  TFR(13) TFR(15) TFR(26) TFR(6)   x0 += ks0; x1 += ks1 + 3u;
  TFR(17) TFR(29) TFR(16) TFR(24)  x0 += ks1; x1 += ks2 + 4u;
  TFR(13) TFR(15) TFR(26) TFR(6)   x0 += ks2; x1 += ks0 + 5u;
#undef TFR
  return x0 ^ x1;
}

// XLA ErfInv32 (Giles).
__device__ __forceinline__ float erfinv_f32(float x) {
  float w = -__logf(fmaf(-x, x, 1.0f));
  float p;
  if (w < 5.0f) {
    w = w - 2.5f;
    p = 2.81022636e-08f;
    p = fmaf(p, w, 3.43273939e-07f);
    p = fmaf(p, w, -3.5233877e-06f);
    p = fmaf(p, w, -4.39150654e-06f);
    p = fmaf(p, w, 0.00021858087f);
    p = fmaf(p, w, -0.00125372503f);
    p = fmaf(p, w, -0.00417768164f);
    p = fmaf(p, w, 0.246640727f);
    p = fmaf(p, w, 1.50140941f);
  } else {
    w = sqrtf(w) - 3.0f;
    p = -0.000200214257f;
    p = fmaf(p, w, 0.000100950558f);
    p = fmaf(p, w, 0.00134934322f);
    p = fmaf(p, w, -0.00367342844f);
    p = fmaf(p, w, 0.00573950773f);
    p = fmaf(p, w, -0.0076224613f);
    p = fmaf(p, w, 0.00943887047f);
    p = fmaf(p, w, 1.00167406f);
    p = fmaf(p, w, 2.83297682f);
  }
  return p * x;
}

__device__ __forceinline__ float jax_normal(uint32_t idx) {
  uint32_t bits = threefry_bits(idx);
  float f = __uint_as_float((bits >> 9) | 0x3F800000u) - 1.0f;  // [0,1)
  const float lo = -0.99999994f;                                 // nextafter(-1,0)
  float u = fmaf(f, 2.0f, lo);
  u = fmaxf(lo, u);
  return 1.41421356f * erfinv_f32(u);
}

// exp-based tanh: ~2ulp. tanh(y)=sign(y)*(1-t)/(1+t), t=exp(-2|y|).
__device__ __forceinline__ float tanh_fast(float y) {
  float ay = fabsf(y);
  float t  = __expf(-2.0f * ay);
  float r  = (1.0f - t) * __frcp_rn(1.0f + t);
  return copysignf(r, y);
}

// LDS-only barrier: orders DS ops without draining vmcnt (keeps global
// out-stores and eta/x pipeline loads in flight).
__device__ __forceinline__ void wg_barrier_lds() {
  asm volatile("s_waitcnt lgkmcnt(0)\n\ts_barrier" ::: "memory");
}

// ---------------- dense noise pre-generation (map kernel) ----------------
__launch_bounds__(256)
__global__ void noise_fill(float* __restrict__ ws) {
  const int64_t nq = (int64_t)ETA_FLOATS / 4;          // float4 groups
  const int64_t stride = (int64_t)gridDim.x * blockDim.x;
  for (int64_t i = (int64_t)blockIdx.x * blockDim.x + threadIdx.x;
       i < nq; i += stride) {
    uint32_t base = (uint32_t)(i * 4);
    float4 v;
    v.x = NOISE_STD_F * jax_normal(base + 0u);
    v.y = NOISE_STD_F * jax_normal(base + 1u);
    v.z = NOISE_STD_F * jax_normal(base + 2u);
    v.w = NOISE_STD_F * jax_normal(base + 3u);
    ((float4*)ws)[i] = v;
  }
}

// ======================= dual-batch anti-phased kernel ===================
// grid 128 x 512 threads. Group grp = tid>>8 owns batch 2*wg+grp.
// Per slot, one group MACs (issue-heavy) while the other UPDATEs
// (latency-heavy) -> each SIMD always has an independent issue stream.
//
// MAC (lt<250): k=lt/50 in [0,5), r=lt%50; rows 4r..4r+3, k-chunk
//   [40k,40k+40) computed as TWO 20-wide sub-chunks written to the 10-slot
//   k-major partial layout -> summation order bit-identical to the
//   verified kernel.
// UPD (lt<200): reduce 10 partials + input drive + tanh + Euler + stores.
//   lt 200..249: eta float4 pipeline (2-UPD-slot slack).
//   lt 250..254: x float2 pipeline (2-UPD-slot slack).

__device__ __forceinline__ void do_mac(
    bool mac_active, const float (&w)[4][40],
    const float* __restrict__ hp,
    float* __restrict__ p0, float* __restrict__ p1) {
  if (!mac_active) return;
  // sub-chunk 0: k-offsets 0..19
  {
    float a0 = 0.0f, a1 = 0.0f, a2 = 0.0f, a3 = 0.0f;
#pragma unroll
    for (int q = 0; q < 5; ++q) {
      float4 hv = *(const float4*)(hp + 4 * q);
      a0 = fmaf(w[0][4 * q + 0], hv.x, a0);
      a1 = fmaf(w[1][4 * q + 0], hv.x, a1);
      a2 = fmaf(w[2][4 * q + 0], hv.x, a2);
      a3 = fmaf(w[3][4 * q + 0], hv.x, a3);
      a0 = fmaf(w[0][4 * q + 1], hv.y, a0);
      a1 = fmaf(w[1][4 * q + 1], hv.y, a1);
      a2 = fmaf(w[2][4 * q + 1], hv.y, a2);
      a3 = fmaf(w[3][4 * q + 1], hv.y, a3);
      a0 = fmaf(w[0][4 * q + 2], hv.z, a0);
      a1 = fmaf(w[1][4 * q + 2], hv.z, a1);
      a2 = fmaf(w[2][4 * q + 2], hv.z, a2);
      a3 = fmaf(w[3][4 * q + 2], hv.z, a3);
      a0 = fmaf(w[0][4 * q + 3], hv.w, a0);
      a1 = fmaf(w[1][4 * q + 3], hv.w, a1);
      a2 = fmaf(w[2][4 * q + 3], hv.w, a2);
      a3 = fmaf(w[3][4 * q + 3], hv.w, a3);
    }
    *(float4*)p0 = make_float4(a0, a1, a2, a3);
  }
  // sub-chunk 1: k-offsets 20..39
  {
    float a0 = 0.0f, a1 = 0.0f, a2 = 0.0f, a3 = 0.0f;
#pragma unroll
    for (int q = 0; q < 5; ++q) {
      float4 hv = *(const float4*)(hp + 20 + 4 * q);
      a0 = fmaf(w[0][20 + 4 * q + 0], hv.x, a0);
      a1 = fmaf(w[1][20 + 4 * q + 0], hv.x, a1);
      a2 = fmaf(w[2][20 + 4 * q + 0], hv.x, a2);
      a3 = fmaf(w[3][20 + 4 * q + 0], hv.x, a3);
      a0 = fmaf(w[0][20 + 4 * q + 1], hv.y, a0);
      a1 = fmaf(w[1][20 + 4 * q + 1], hv.y, a1);
      a2 = fmaf(w[2][20 + 4 * q + 1], hv.y, a2);
      a3 = fmaf(w[3][20 + 4 * q + 1], hv.y, a3);
      a0 = fmaf(w[0][20 + 4 * q + 2], hv.z, a0);
      a1 = fmaf(w[1][20 + 4 * q + 2], hv.z, a1);
      a2 = fmaf(w[2][20 + 4 * q + 2], hv.z, a2);
      a3 = fmaf(w[3][20 + 4 * q + 2], hv.z, a3);
      a0 = fmaf(w[0][20 + 4 * q + 3], hv.w, a0);
      a1 = fmaf(w[1][20 + 4 * q + 3], hv.w, a1);
      a2 = fmaf(w[2][20 + 4 * q + 3], hv.w, a2);
      a3 = fmaf(w[3][20 + 4 * q + 3], hv.w, a3);
    }
    *(float4*)p1 = make_float4(a0, a1, a2, a3);
  }
}

template <int CUR, bool PF>
__device__ __forceinline__ void do_upd(
    int t, int lt,
    const float (&winp)[NI], float brec_r, float& h_reg, float*& obp,
    float4& enA, float4& enB, float2& xnA, float2& xnB,
    const float* __restrict__ xb, const float* __restrict__ etab,
    float* __restrict__ g_h, const float* __restrict__ g_part,
    float (*__restrict__ g_x)[16], float (*__restrict__ g_eta)[NR]) {
  constexpr int NXT = CUR ^ 1;
  if (lt < NR) {
    float y = brec_r;
#pragma unroll
    for (int q = 0; q < 10; ++q) y += g_part[q * NR + lt];
    float4 xv0 = *(const float4*)(&g_x[CUR][0]);
    float4 xv1 = *(const float4*)(&g_x[CUR][4]);
    float2 xv2 = *(const float2*)(&g_x[CUR][8]);
    y = fmaf(winp[0], xv0.x, y);
    y = fmaf(winp[1], xv0.y, y);
    y = fmaf(winp[2], xv0.z, y);
    y = fmaf(winp[3], xv0.w, y);
    y = fmaf(winp[4], xv1.x, y);
    y = fmaf(winp[5], xv1.y, y);
    y = fmaf(winp[6], xv1.z, y);
    y = fmaf(winp[7], xv1.w, y);
    y = fmaf(winp[8], xv2.x, y);
    y = fmaf(winp[9], xv2.y, y);
    float rate = tanh_fast(y);
    float eta  = g_eta[CUR][lt];
    float hn = h_reg + ALPHA_F * (((-h_reg) + rate) + eta);
    h_reg = hn;
    g_h[lt] = hn;
    *obp = hn;
    obp += NR;
  } else if (lt < 250) {
    if (PF) {
      int j = lt - 200;
      *(float4*)(&g_eta[NXT][4 * j]) = (CUR == 0) ? enA : enB;
      int tf = t + 3;
      if (tf > TSTEPS - 1) tf = TSTEPS - 1;   // harmless redundant tail load
      float4 e = *(const float4*)(etab + (size_t)tf * ETA_STRIDE + 4 * j);
      if (CUR == 0) enA = e; else enB = e;
    }
  } else if (lt < 255) {
    if (PF) {
      int j = lt - 250;                        // handles x floats 2j, 2j+1
      *(float2*)(&g_x[NXT][2 * j]) = (CUR == 0) ? xnA : xnB;
      int tf = t + 3;
      if (tf > TSTEPS - 1) tf = TSTEPS - 1;
      float2 xl = *(const float2*)(xb + tf * NI + 2 * j);
      if (CUR == 0) xnA = xl; else xnB = xl;
    }
  }
}

__launch_bounds__(512, 2)
__global__ void rnn_dual(const float* __restrict__ x,
                         const float* __restrict__ h0,
                         const float* __restrict__ Winp,
                         const float* __restrict__ Wrec,
                         const float* __restrict__ brec,
                         const float* __restrict__ eta_ws,
                         float* __restrict__ out) {
  const int wg  = blockIdx.x;          // 0..127
  const int tid = threadIdx.x;
  const int grp = tid >> 8;            // 0 or 1
  const int lt  = tid & 255;
  const int b   = 2 * wg + grp;

  __shared__ float sh_h[2][NR];
  __shared__ float sh_part[2][10 * NR];
  __shared__ float sh_x[2][2][16];
  __shared__ float sh_eta[2][2][NR];

  float* g_h    = sh_h[grp];
  float* g_part = sh_part[grp];
  float (*g_x)[16]  = sh_x[grp];
  float (*g_eta)[NR] = sh_eta[grp];

  const int  k_th = lt / 50;
  const int  r_th = lt % 50;
  const bool mac_active = (lt < 250);

  // --- stationary W_rec tile: 4 rows x 40 k-values (~160 regs, unified) ---
  float w[4][40];
  if (mac_active) {
#pragma unroll
    for (int j = 0; j < 4; ++j) {
      const float* wr = Wrec + (size_t)(4 * r_th + j) * NR + 40 * k_th;
#pragma unroll
      for (int q = 0; q < 10; ++q) {
        float4 v = *(const float4*)(wr + 4 * q);
        w[j][4 * q + 0] = v.x; w[j][4 * q + 1] = v.y;
        w[j][4 * q + 2] = v.z; w[j][4 * q + 3] = v.w;
      }
    }
  }

  // --- update-thread state ---
  float winp[NI];
  float brec_r = 0.0f;
  float h_reg  = 0.0f;
  float* obp   = nullptr;

  const float* xb   = x + (size_t)b * TSTEPS * NI;
  const float* etab = eta_ws + (size_t)b * NR;
  float* ob         = out + (size_t)b * TSTEPS * NR;

  if (lt < NR) {
#pragma unroll
    for (int i = 0; i < NI; ++i) winp[i] = Winp[lt * NI + i];
    brec_r = brec[lt];
    h_reg  = h0[(size_t)b * NR + lt];
    g_h[lt] = h_reg;
    obp = ob + lt;
  }

  float4 enA = make_float4(0.f, 0.f, 0.f, 0.f);
  float4 enB = make_float4(0.f, 0.f, 0.f, 0.f);
  float2 xnA = make_float2(0.f, 0.f);
  float2 xnB = make_float2(0.f, 0.f);

  // --- bootstrap: eta(0)/x(0) -> buf0; (1),(2) -> pipeline regs ---
  if (lt >= 200 && lt < 250) {
    int j = lt - 200;
    *(float4*)(&g_eta[0][4 * j]) = *(const float4*)(etab + 4 * j);
    enA = *(const float4*)(etab + (size_t)1 * ETA_STRIDE + 4 * j);  // eta(1)
    enB = *(const float4*)(etab + (size_t)2 * ETA_STRIDE + 4 * j);  // eta(2)
  } else if (lt >= 250 && lt < 255) {
    int j = lt - 250;
    *(float2*)(&g_x[0][2 * j]) = *(const float2*)(xb + 2 * j);      // x(0)
    xnA = *(const float2*)(xb + NI + 2 * j);                        // x(1)
    xnB = *(const float2*)(xb + 2 * NI + 2 * j);                    // x(2)
  }
  __syncthreads();

  const float* hp = g_h + 40 * k_th;
  float* p0 = g_part + (size_t)(2 * k_th) * NR + 4 * r_th;
  float* p1 = g_part + (size_t)(2 * k_th + 1) * NR + 4 * r_th;

  // ---- slot 0: G0 MAC(0), G1 idle ----
  if (grp == 0) do_mac(mac_active, w, hp, p0, p1);
  wg_barrier_lds();

  // ---- L(i): slotB(i) = {G0 UPD(i) || G1 MAC(i)}; bar;
  //            slotA(i+1) = {G0 MAC(i+1) || G1 UPD(i)}; bar. ----
#define SLOT_B(I, C, P)                                                     \
  if (grp == 0) do_upd<C, P>((I), lt, winp, brec_r, h_reg, obp, enA, enB,   \
                             xnA, xnB, xb, etab, g_h, g_part, g_x, g_eta);  \
  else          do_mac(mac_active, w, hp, p0, p1);                          \
  wg_barrier_lds();
#define SLOT_A(I, C, P)                                                     \
  if (grp == 0) do_mac(mac_active, w, hp, p0, p1);                          \
  else          do_upd<C, P>((I)-1, lt, winp, brec_r, h_reg, obp, enA, enB, \
                             xnA, xnB, xb, etab, g_h, g_part, g_x, g_eta);  \
  wg_barrier_lds();

  for (int i = 0; i < TSTEPS - 2; i += 2) {   // i = 0,2,...,996
    SLOT_B(i,     0, true)
    SLOT_A(i + 1, 0, true)
    SLOT_B(i + 1, 1, true)
    SLOT_A(i + 2, 1, true)
  }
  // L(998):
  SLOT_B(TSTEPS - 2, 0, true)
  SLOT_A(TSTEPS - 1, 0, true)
  // final slotB(999): G0 UPD(999, no PF) || G1 MAC(999)
  SLOT_B(TSTEPS - 1, 1, false)
  // epilogue: G1 UPD(999, no PF)
  if (grp == 1) {
    do_upd<1, false>(TSTEPS - 1, lt, winp, brec_r, h_reg, obp, enA, enB,
                     xnA, xnB, xb, etab, g_h, g_part, g_x, g_eta);
  }
#undef SLOT_A
#undef SLOT_B
}

// ================== fallback: verified R1-style kernel ===================
// (in-kernel noise, 1 batch per 512-thread WG; used only if workspace is
// unavailable — proven 898 us rocprof.)
template <int CUR, bool PF>
__device__ __forceinline__ void fb_step(
    int t, int tid, bool mac_active,
    const float (&w)[4][20], const float (&winp)[NI], float brec_r,
    float& h_reg, float*& obp, float& xnA, float& xnB,
    const float* __restrict__ xb, uint32_t nb_b,
    const float* __restrict__ hp, float* __restrict__ part_wp,
    float* __restrict__ sh_h, float* __restrict__ sh_part,
    float (*__restrict__ sh_x)[16], float (*__restrict__ sh_eta)[NR]) {
  constexpr int NXT = CUR ^ 1;
  if (mac_active) {
    float a0 = 0.0f, a1 = 0.0f, a2 = 0.0f, a3 = 0.0f;
#pragma unroll
    for (int q = 0; q < 5; ++q) {
      float4 hv = *(const float4*)(hp + 4 * q);
      a0 = fmaf(w[0][4 * q + 0], hv.x, a0);
      a1 = fmaf(w[1][4 * q + 0], hv.x, a1);
      a2 = fmaf(w[2][4 * q + 0], hv.x, a2);
      a3 = fmaf(w[3][4 * q + 0], hv.x, a3);
      a0 = fmaf(w[0][4 * q + 1], hv.y, a0);
      a1 = fmaf(w[1][4 * q + 1], hv.y, a1);
      a2 = fmaf(w[2][4 * q + 1], hv.y, a2);
      a3 = fmaf(w[3][4 * q + 1], hv.y, a3);
      a0 = fmaf(w[0][4 * q + 2], hv.z, a0);
      a1 = fmaf(w[1][4 * q + 2], hv.z, a1);
      a2 = fmaf(w[2][4 * q + 2], hv.z, a2);
      a3 = fmaf(w[3][4 * q + 2], hv.z, a3);
      a0 = fmaf(w[0][4 * q + 3], hv.w, a0);
      a1 = fmaf(w[1][4 * q + 3], hv.w, a1);
      a2 = fmaf(w[2][4 * q + 3], hv.w, a2);
      a3 = fmaf(w[3][4 * q + 3], hv.w, a3);
    }
    *(float4*)part_wp = make_float4(a0, a1, a2, a3);
  }
  wg_barrier_lds();
  if (tid < NR) {
    float y = brec_r;
#pragma unroll
    for (int q = 0; q < 10; ++q) y += sh_part[q * NR + tid];
    float4 xv0 = *(const float4*)(&sh_x[CUR][0]);
    float4 xv1 = *(const float4*)(&sh_x[CUR][4]);
    float2 xv2 = *(const float2*)(&sh_x[CUR][8]);
    y = fmaf(winp[0], xv0.x, y);
    y = fmaf(winp[1], xv0.y, y);
    y = fmaf(winp[2], xv0.z, y);
    y = fmaf(winp[3], xv0.w, y);
    y = fmaf(winp[4], xv1.x, y);
    y = fmaf(winp[5], xv1.y, y);
    y = fmaf(winp[6], xv1.z, y);
    y = fmaf(winp[7], xv1.w, y);
    y = fmaf(winp[8], xv2.x, y);
    y = fmaf(winp[9], xv2.y, y);
    float rate = tanh_fast(y);
    float eta  = sh_eta[CUR][tid];
    float hn = h_reg + ALPHA_F * (((-h_reg) + rate) + eta);
    h_reg = hn;
    sh_h[tid] = hn;
    *obp = hn;
    obp += NR;
  } else if ((tid >= 256 && tid < 448) || (tid < 208)) {
    if (PF) {
      int n = (tid >= 256) ? (tid - 256) : (tid - 8);
      uint32_t idx = (uint32_t)(t + 1) * (uint32_t)(NB * NR) + nb_b + (uint32_t)n;
      sh_eta[NXT][n] = NOISE_STD_F * jax_normal(idx);
    }
  } else if (tid >= 448 && tid < 448 + NI) {
    if (PF) {
      int j = tid - 448;
      sh_x[NXT][j] = (CUR == 0) ? xnA : xnB;
      int tf = t + 3;
      if (tf > TSTEPS - 1) tf = TSTEPS - 1;
      float xl = xb[tf * NI + j];
      if (CUR == 0) xnA = xl; else xnB = xl;
    }
  }
  wg_barrier_lds();
}

__global__ __launch_bounds__(512, 2)
void rnn_fallback(const float* __restrict__ x,
                  const float* __restrict__ h0,
                  const float* __restrict__ Winp,
                  const float* __restrict__ Wrec,
                  const float* __restrict__ brec,
                  float* __restrict__ out) {
  const int b   = blockIdx.x;
  const int tid = threadIdx.x;
  __shared__ float sh_h[NR];
  __shared__ float sh_part[10 * NR];
  __shared__ float sh_x[2][16];
  __shared__ float sh_eta[2][NR];
  const int  k_th = tid / 50;
  const int  r_th = tid % 50;
  const bool mac_active = (tid < 500);
  float w[4][20];
  if (mac_active) {
#pragma unroll
    for (int j = 0; j < 4; ++j) {
      const float* wr = Wrec + (size_t)(4 * r_th + j) * NR + 20 * k_th;
#pragma unroll
      for (int q = 0; q < 5; ++q) {
        float4 v = *(const float4*)(wr + 4 * q);
        w[j][4 * q + 0] = v.x; w[j][4 * q + 1] = v.y;
        w[j][4 * q + 2] = v.z; w[j][4 * q + 3] = v.w;
      }
    }
  }
  float winp[NI];
  float brec_r = 0.0f, h_reg = 0.0f;
  float* obp = nullptr;
  const float* xb = x + (size_t)b * TSTEPS * NI;
  float* ob       = out + (size_t)b * TSTEPS * NR;
  if (tid < NR) {
#pragma unroll
    for (int i = 0; i < NI; ++i) winp[i] = Winp[tid * NI + i];
    brec_r = brec[tid];
    h_reg  = h0[(size_t)b * NR + tid];
    sh_h[tid] = h_reg;
    obp = ob + tid;
  }
  const uint32_t nb_b = (uint32_t)b * (uint32_t)NR;
  float xnA = 0.0f, xnB = 0.0f;
  if ((tid >= 256 && tid < 448) || (tid >= 200 && tid < 208)) {
    int n = (tid >= 256) ? (tid - 256) : (tid - 8);
    sh_eta[0][n] = NOISE_STD_F * jax_normal(nb_b + (uint32_t)n);
  }
  if (tid >= 448 && tid < 448 + NI) {
    int j = tid - 448;
    sh_x[0][j] = xb[j];
    xnA = xb[NI + j];
    xnB = xb[2 * NI + j];
  }
  __syncthreads();
  const float* hp      = sh_h + 20 * k_th;
  float*       part_wp = sh_part + k_th * NR + 4 * r_th;
  for (int t = 0; t < TSTEPS - 2; t += 2) {
    fb_step<0, true>(t,     tid, mac_active, w, winp, brec_r, h_reg, obp,
                     xnA, xnB, xb, nb_b, hp, part_wp, sh_h, sh_part, sh_x, sh_eta);
    fb_step<1, true>(t + 1, tid, mac_active, w, winp, brec_r, h_reg, obp,
                     xnA, xnB, xb, nb_b, hp, part_wp, sh_h, sh_part, sh_x, sh_eta);
  }
  fb_step<0, true >(TSTEPS - 2, tid, mac_active, w, winp, brec_r, h_reg, obp,
                    xnA, xnB, xb, nb_b, hp, part_wp, sh_h, sh_part, sh_x, sh_eta);
  fb_step<1, false>(TSTEPS - 1, tid, mac_active, w, winp, brec_r, h_reg, obp,
                    xnA, xnB, xb, nb_b, hp, part_wp, sh_h, sh_part, sh_x, sh_eta);
}

extern "C" void kernel_launch(void* const* d_in, const int* in_sizes, int n_in,
                              void* d_out, int out_size, void* d_ws, size_t ws_size,
                              hipStream_t stream) {
  const float* x    = (const float*)d_in[0];  // [256,1000,10]
  const float* h0   = (const float*)d_in[1];  // [256,200]
  const float* Winp = (const float*)d_in[2];  // [200,10]
  const float* Wrec = (const float*)d_in[3];  // [200,200]
  const float* brec = (const float*)d_in[4];  // [200]
  float* out = (float*)d_out;                 // [256,1000,200]
  (void)in_sizes; (void)n_in; (void)out_size;

  const size_t eta_bytes = ETA_FLOATS * sizeof(float);  // 204.8 MB
  if (d_ws != nullptr && ws_size >= eta_bytes) {
    noise_fill<<<dim3(4096), dim3(256), 0, stream>>>((float*)d_ws);
    rnn_dual<<<dim3(NB / 2), dim3(512), 0, stream>>>(
        x, h0, Winp, Wrec, brec, (const float*)d_ws, out);
  } else {
    rnn_fallback<<<dim3(NB), dim3(512), 0, stream>>>(
        x, h0, Winp, Wrec, brec, out);
  }
}

// Round 5
// 1421.231 us; speedup vs baseline: 1.2374x; 1.2374x over previous
//
#include <hip/hip_runtime.h>
#include <cstdint>
#include <cstddef>

#define TSTEPS 1000
#define NB     256
#define NR     200
#define NI     10
#define ALPHA_F     0.1f
#define NOISE_STD_F 0.01f
#define ETA_STRIDE  (NB * NR)          // 51200 floats per timestep
#define ETA_FLOATS  ((size_t)TSTEPS * NB * NR)

// ---------------- JAX threefry2x32-20, key = (0, 42) --------------------
__device__ __forceinline__ uint32_t rotl32(uint32_t v, uint32_t d) {
  return (v << d) | (v >> (32u - d));
}

__device__ __forceinline__ uint32_t threefry_bits(uint32_t c1) {
  const uint32_t ks0 = 0u;
  const uint32_t ks1 = 42u;
  const uint32_t ks2 = 0x1BD11BDAu ^ ks0 ^ ks1;
  uint32_t x0 = ks0;
  uint32_t x1 = c1 + ks1;
#define TFR(r) { x0 += x1; x1 = rotl32(x1, (r)); x1 ^= x0; }
  TFR(13) TFR(15) TFR(26) TFR(6)   x0 += ks1; x1 += ks2 + 1u;
  TFR(17) TFR(29) TFR(16) TFR(24)  x0 += ks2; x1 += ks0 + 2u;
  TFR(13) TFR(15) TFR(26) TFR(6)   x0 += ks0; x1 += ks1 + 3u;
  TFR(17) TFR(29) TFR(16) TFR(24)  x0 += ks1; x1 += ks2 + 4u;
  TFR(13) TFR(15) TFR(26) TFR(6)   x0 += ks2; x1 += ks0 + 5u;
#undef TFR
  return x0 ^ x1;
}

// XLA ErfInv32 (Giles).
__device__ __forceinline__ float erfinv_f32(float x) {
  float w = -__logf(fmaf(-x, x, 1.0f));
  float p;
  if (w < 5.0f) {
    w = w - 2.5f;
    p = 2.81022636e-08f;
    p = fmaf(p, w, 3.43273939e-07f);
    p = fmaf(p, w, -3.5233877e-06f);
    p = fmaf(p, w, -4.39150654e-06f);
    p = fmaf(p, w, 0.00021858087f);
    p = fmaf(p, w, -0.00125372503f);
    p = fmaf(p, w, -0.00417768164f);
    p = fmaf(p, w, 0.246640727f);
    p = fmaf(p, w, 1.50140941f);
  } else {
    w = sqrtf(w) - 3.0f;
    p = -0.000200214257f;
    p = fmaf(p, w, 0.000100950558f);
    p = fmaf(p, w, 0.00134934322f);
    p = fmaf(p, w, -0.00367342844f);
    p = fmaf(p, w, 0.00573950773f);
    p = fmaf(p, w, -0.0076224613f);
    p = fmaf(p, w, 0.00943887047f);
    p = fmaf(p, w, 1.00167406f);
    p = fmaf(p, w, 2.83297682f);
  }
  return p * x;
}

__device__ __forceinline__ float jax_normal(uint32_t idx) {
  uint32_t bits = threefry_bits(idx);
  float f = __uint_as_float((bits >> 9) | 0x3F800000u) - 1.0f;  // [0,1)
  const float lo = -0.99999994f;                                 // nextafter(-1,0)
  float u = fmaf(f, 2.0f, lo);
  u = fmaxf(lo, u);
  return 1.41421356f * erfinv_f32(u);
}

// exp-based tanh: ~2ulp. tanh(y)=sign(y)*(1-t)/(1+t), t=exp(-2|y|).
__device__ __forceinline__ float tanh_fast(float y) {
  float ay = fabsf(y);
  float t  = __expf(-2.0f * ay);
  float r  = (1.0f - t) * __frcp_rn(1.0f + t);
  return copysignf(r, y);
}

// LDS-only barrier: orders DS ops without draining vmcnt (keeps global
// out-stores and eta/x pipeline loads in flight).
__device__ __forceinline__ void wg_barrier_lds() {
  asm volatile("s_waitcnt lgkmcnt(0)\n\ts_barrier" ::: "memory");
}

// ---------------- dense noise pre-generation (map kernel) ----------------
__launch_bounds__(256)
__global__ void noise_fill(float* __restrict__ ws) {
  const int64_t nq = (int64_t)ETA_FLOATS / 4;          // float4 groups
  const int64_t stride = (int64_t)gridDim.x * blockDim.x;
  for (int64_t i = (int64_t)blockIdx.x * blockDim.x + threadIdx.x;
       i < nq; i += stride) {
    uint32_t base = (uint32_t)(i * 4);
    float4 v;
    v.x = NOISE_STD_F * jax_normal(base + 0u);
    v.y = NOISE_STD_F * jax_normal(base + 1u);
    v.z = NOISE_STD_F * jax_normal(base + 2u);
    v.w = NOISE_STD_F * jax_normal(base + 3u);
    ((float4*)ws)[i] = v;
  }
}

// ============== full-row-per-thread kernel: ONE barrier/step =============
// 256 threads = 4 waves = 1 wave/SIMD. Per wave (wv=tid>>6, ln=tid&63):
//   ln<50        : owns row r=wv*50+ln. Full 200-wide dot from broadcast
//                  ds_read_b128 of sh_h[CUR], in the SAME 10x20-chunk
//                  order (p per chunk, y+=p) as the verified kernel ->
//                  bit-identical. tanh + Euler + sh_h[NXT] + out store.
//   ln 50..62    : eta float4 pipeline slot e=wv*13+(ln-50), active e<50
//                  (2-step global-load slack; write sh_eta[NXT]).
//   ln==63       : x float2 pipeline j=wv; plus wave3/ln61 (spare eta
//                  slot) handles j=4. Covers all 10 x floats.
// W_rec row lives in 200 NAMED scalar registers (no arrays -> no scratch;
// R2's indexed-array spill is the failure this avoids).

#define DECLW(q) \
  float W_##q##_0 = 0.f, W_##q##_1 = 0.f, W_##q##_2 = 0.f, W_##q##_3 = 0.f, \
        W_##q##_4 = 0.f, W_##q##_5 = 0.f, W_##q##_6 = 0.f, W_##q##_7 = 0.f, \
        W_##q##_8 = 0.f, W_##q##_9 = 0.f, W_##q##_10 = 0.f, W_##q##_11 = 0.f,\
        W_##q##_12 = 0.f, W_##q##_13 = 0.f, W_##q##_14 = 0.f,               \
        W_##q##_15 = 0.f, W_##q##_16 = 0.f, W_##q##_17 = 0.f,               \
        W_##q##_18 = 0.f, W_##q##_19 = 0.f;

#define LOADW(q) {                                                          \
  const float* wp_ = wr + 20 * (q);                                         \
  float4 a_  = *(const float4*)(wp_);                                       \
  float4 b_  = *(const float4*)(wp_ + 4);                                   \
  float4 c_  = *(const float4*)(wp_ + 8);                                   \
  float4 d_  = *(const float4*)(wp_ + 12);                                  \
  float4 e4_ = *(const float4*)(wp_ + 16);                                  \
  W_##q##_0  = a_.x;  W_##q##_1  = a_.y;  W_##q##_2  = a_.z;                \
  W_##q##_3  = a_.w;  W_##q##_4  = b_.x;  W_##q##_5  = b_.y;                \
  W_##q##_6  = b_.z;  W_##q##_7  = b_.w;  W_##q##_8  = c_.x;                \
  W_##q##_9  = c_.y;  W_##q##_10 = c_.z;  W_##q##_11 = c_.w;                \
  W_##q##_12 = d_.x;  W_##q##_13 = d_.y;  W_##q##_14 = d_.z;                \
  W_##q##_15 = d_.w;  W_##q##_16 = e4_.x; W_##q##_17 = e4_.y;               \
  W_##q##_18 = e4_.z; W_##q##_19 = e4_.w; }

#define FMAC(q) {                                                           \
  const float* hq_ = hb + 20 * (q);                                         \
  float4 a_  = *(const float4*)(hq_);                                       \
  float4 b_  = *(const float4*)(hq_ + 4);                                   \
  float4 c_  = *(const float4*)(hq_ + 8);                                   \
  float4 d_  = *(const float4*)(hq_ + 12);                                  \
  float4 e4_ = *(const float4*)(hq_ + 16);                                  \
  float p_ = 0.0f;                                                          \
  p_ = fmaf(W_##q##_0,  a_.x,  p_);                                         \
  p_ = fmaf(W_##q##_1,  a_.y,  p_);                                         \
  p_ = fmaf(W_##q##_2,  a_.z,  p_);                                         \
  p_ = fmaf(W_##q##_3,  a_.w,  p_);                                         \
  p_ = fmaf(W_##q##_4,  b_.x,  p_);                                         \
  p_ = fmaf(W_##q##_5,  b_.y,  p_);                                         \
  p_ = fmaf(W_##q##_6,  b_.z,  p_);                                         \
  p_ = fmaf(W_##q##_7,  b_.w,  p_);                                         \
  p_ = fmaf(W_##q##_8,  c_.x,  p_);                                         \
  p_ = fmaf(W_##q##_9,  c_.y,  p_);                                         \
  p_ = fmaf(W_##q##_10, c_.z,  p_);                                         \
  p_ = fmaf(W_##q##_11, c_.w,  p_);                                         \
  p_ = fmaf(W_##q##_12, d_.x,  p_);                                         \
  p_ = fmaf(W_##q##_13, d_.y,  p_);                                         \
  p_ = fmaf(W_##q##_14, d_.z,  p_);                                         \
  p_ = fmaf(W_##q##_15, d_.w,  p_);                                         \
  p_ = fmaf(W_##q##_16, e4_.x, p_);                                         \
  p_ = fmaf(W_##q##_17, e4_.y, p_);                                         \
  p_ = fmaf(W_##q##_18, e4_.z, p_);                                         \
  p_ = fmaf(W_##q##_19, e4_.w, p_);                                         \
  y += p_; }

// One step. CURI is a literal 0/1; TT the timestep; PF_ prefetch enable.
#define STEP(CURI, TT, PF_) {                                               \
  if (ln < 50) {                                                            \
    const float* hb = sh_h[CURI];                                           \
    float y = brec_r;                                                       \
    FMAC(0) FMAC(1) FMAC(2) FMAC(3) FMAC(4)                                 \
    FMAC(5) FMAC(6) FMAC(7) FMAC(8) FMAC(9)                                 \
    float4 xv0 = *(const float4*)(&sh_x[CURI][0]);                          \
    float4 xv1 = *(const float4*)(&sh_x[CURI][4]);                          \
    float2 xv2 = *(const float2*)(&sh_x[CURI][8]);                          \
    y = fmaf(winp0, xv0.x, y);                                              \
    y = fmaf(winp1, xv0.y, y);                                              \
    y = fmaf(winp2, xv0.z, y);                                              \
    y = fmaf(winp3, xv0.w, y);                                              \
    y = fmaf(winp4, xv1.x, y);                                              \
    y = fmaf(winp5, xv1.y, y);                                              \
    y = fmaf(winp6, xv1.z, y);                                              \
    y = fmaf(winp7, xv1.w, y);                                              \
    y = fmaf(winp8, xv2.x, y);                                              \
    y = fmaf(winp9, xv2.y, y);                                              \
    float rate = tanh_fast(y);                                              \
    float eta  = sh_eta[CURI][row];                                         \
    float hn = h_reg + ALPHA_F * (((-h_reg) + rate) + eta);                 \
    h_reg = hn;                                                             \
    sh_h[(CURI) ^ 1][row] = hn;                                             \
    *obp = hn;                                                              \
    obp += NR;                                                              \
  } else if (elane) {                                                       \
    if (PF_) {                                                              \
      *(float4*)(&sh_eta[(CURI) ^ 1][4 * eidx]) =                           \
          ((CURI) == 0) ? enA : enB;                                        \
      int tf = (TT) + 3;                                                    \
      if (tf > TSTEPS - 1) tf = TSTEPS - 1;                                 \
      float4 e_ = *(const float4*)(etab + (size_t)tf * ETA_STRIDE + 4 * eidx);\
      if ((CURI) == 0) enA = e_; else enB = e_;                             \
    }                                                                       \
  } else if (xlane) {                                                       \
    if (PF_) {                                                              \
      *(float2*)(&sh_x[(CURI) ^ 1][2 * xj]) = ((CURI) == 0) ? xnA : xnB;    \
      int tf = (TT) + 3;                                                    \
      if (tf > TSTEPS - 1) tf = TSTEPS - 1;                                 \
      float2 x_ = *(const float2*)(xb + tf * NI + 2 * xj);                  \
      if ((CURI) == 0) xnA = x_; else xnB = x_;                             \
    }                                                                       \
  }                                                                         \
  wg_barrier_lds(); }

__launch_bounds__(256, 1)
__global__ void rnn_rowreg(const float* __restrict__ x,
                           const float* __restrict__ h0,
                           const float* __restrict__ Winp,
                           const float* __restrict__ Wrec,
                           const float* __restrict__ brec,
                           const float* __restrict__ eta_ws,
                           float* __restrict__ out) {
  const int b   = blockIdx.x;
  const int tid = threadIdx.x;
  const int wv  = tid >> 6;
  const int ln  = tid & 63;

  __shared__ float sh_h[2][NR];    // double-buffered hidden state
  __shared__ float sh_eta[2][NR];  // scaled-noise double buffer
  __shared__ float sh_x[2][16];    // x_t double buffer

  const int  row  = wv * 50 + ln;                 // valid iff ln<50
  const int  eidx = wv * 13 + (ln - 50);          // eta float4 slot
  const bool elane = (ln >= 50) && (ln < 63) && (eidx < 50);
  const bool xlane = (ln == 63) || (wv == 3 && ln == 61);  // spare eta slot
  const int  xj    = (ln == 63) ? wv : 4;

  const float* xb   = x + (size_t)b * TSTEPS * NI;
  const float* etab = eta_ws + (size_t)b * NR;
  float* ob         = out + (size_t)b * TSTEPS * NR;

  // --- W_rec row in 200 named scalars (no dynamic indexing) ---
  DECLW(0) DECLW(1) DECLW(2) DECLW(3) DECLW(4)
  DECLW(5) DECLW(6) DECLW(7) DECLW(8) DECLW(9)
  float winp0 = 0.f, winp1 = 0.f, winp2 = 0.f, winp3 = 0.f, winp4 = 0.f;
  float winp5 = 0.f, winp6 = 0.f, winp7 = 0.f, winp8 = 0.f, winp9 = 0.f;
  float brec_r = 0.0f;
  float h_reg  = 0.0f;
  float* obp   = nullptr;
  float4 enA = make_float4(0.f, 0.f, 0.f, 0.f);
  float4 enB = make_float4(0.f, 0.f, 0.f, 0.f);
  float2 xnA = make_float2(0.f, 0.f);
  float2 xnB = make_float2(0.f, 0.f);

  if (ln < 50) {
    const float* wr = Wrec + (size_t)row * NR;
    LOADW(0) LOADW(1) LOADW(2) LOADW(3) LOADW(4)
    LOADW(5) LOADW(6) LOADW(7) LOADW(8) LOADW(9)
    const float* wi = Winp + (size_t)row * NI;
    winp0 = wi[0]; winp1 = wi[1]; winp2 = wi[2]; winp3 = wi[3];
    winp4 = wi[4]; winp5 = wi[5]; winp6 = wi[6]; winp7 = wi[7];
    winp8 = wi[8]; winp9 = wi[9];
    brec_r = brec[row];
    h_reg  = h0[(size_t)b * NR + row];
    sh_h[0][row] = h_reg;
    obp = ob + row;
  } else if (elane) {
    *(float4*)(&sh_eta[0][4 * eidx]) = *(const float4*)(etab + 4 * eidx);
    enA = *(const float4*)(etab + (size_t)1 * ETA_STRIDE + 4 * eidx);  // t=1
    enB = *(const float4*)(etab + (size_t)2 * ETA_STRIDE + 4 * eidx);  // t=2
  } else if (xlane) {
    *(float2*)(&sh_x[0][2 * xj]) = *(const float2*)(xb + 2 * xj);      // t=0
    xnA = *(const float2*)(xb + NI + 2 * xj);                          // t=1
    xnB = *(const float2*)(xb + 2 * NI + 2 * xj);                      // t=2
  }
  __syncthreads();

  for (int t = 0; t < TSTEPS - 2; t += 2) {
    STEP(0, t,     true)
    STEP(1, t + 1, true)
  }
  STEP(0, TSTEPS - 2, true)
  STEP(1, TSTEPS - 1, false)
}

// ================== fallback: verified R1-style kernel ===================
// (in-kernel noise; used only if workspace is unavailable — 898 us rocprof.)
template <int CUR, bool PF>
__device__ __forceinline__ void fb_step(
    int t, int tid, bool mac_active,
    const float (&w)[4][20], const float (&winp)[NI], float brec_r,
    float& h_reg, float*& obp, float& xnA, float& xnB,
    const float* __restrict__ xb, uint32_t nb_b,
    const float* __restrict__ hp, float* __restrict__ part_wp,
    float* __restrict__ sh_h, float* __restrict__ sh_part,
    float (*__restrict__ sh_x)[16], float (*__restrict__ sh_eta)[NR]) {
  constexpr int NXT = CUR ^ 1;
  if (mac_active) {
    float a0 = 0.0f, a1 = 0.0f, a2 = 0.0f, a3 = 0.0f;
#pragma unroll
    for (int q = 0; q < 5; ++q) {
      float4 hv = *(const float4*)(hp + 4 * q);
      a0 = fmaf(w[0][4 * q + 0], hv.x, a0);
      a1 = fmaf(w[1][4 * q + 0], hv.x, a1);
      a2 = fmaf(w[2][4 * q + 0], hv.x, a2);
      a3 = fmaf(w[3][4 * q + 0], hv.x, a3);
      a0 = fmaf(w[0][4 * q + 1], hv.y, a0);
      a1 = fmaf(w[1][4 * q + 1], hv.y, a1);
      a2 = fmaf(w[2][4 * q + 1], hv.y, a2);
      a3 = fmaf(w[3][4 * q + 1], hv.y, a3);
      a0 = fmaf(w[0][4 * q + 2], hv.z, a0);
      a1 = fmaf(w[1][4 * q + 2], hv.z, a1);
      a2 = fmaf(w[2][4 * q + 2], hv.z, a2);
      a3 = fmaf(w[3][4 * q + 2], hv.z, a3);
      a0 = fmaf(w[0][4 * q + 3], hv.w, a0);
      a1 = fmaf(w[1][4 * q + 3], hv.w, a1);
      a2 = fmaf(w[2][4 * q + 3], hv.w, a2);
      a3 = fmaf(w[3][4 * q + 3], hv.w, a3);
    }
    *(float4*)part_wp = make_float4(a0, a1, a2, a3);
  }
  wg_barrier_lds();
  if (tid < NR) {
    float y = brec_r;
#pragma unroll
    for (int q = 0; q < 10; ++q) y += sh_part[q * NR + tid];
    float4 xv0 = *(const float4*)(&sh_x[CUR][0]);
    float4 xv1 = *(const float4*)(&sh_x[CUR][4]);
    float2 xv2 = *(const float2*)(&sh_x[CUR][8]);
    y = fmaf(winp[0], xv0.x, y);
    y = fmaf(winp[1], xv0.y, y);
    y = fmaf(winp[2], xv0.z, y);
    y = fmaf(winp[3], xv0.w, y);
    y = fmaf(winp[4], xv1.x, y);
    y = fmaf(winp[5], xv1.y, y);
    y = fmaf(winp[6], xv1.z, y);
    y = fmaf(winp[7], xv1.w, y);
    y = fmaf(winp[8], xv2.x, y);
    y = fmaf(winp[9], xv2.y, y);
    float rate = tanh_fast(y);
    float eta  = sh_eta[CUR][tid];
    float hn = h_reg + ALPHA_F * (((-h_reg) + rate) + eta);
    h_reg = hn;
    sh_h[tid] = hn;
    *obp = hn;
    obp += NR;
  } else if ((tid >= 256 && tid < 448) || (tid < 208)) {
    if (PF) {
      int n = (tid >= 256) ? (tid - 256) : (tid - 8);
      uint32_t idx = (uint32_t)(t + 1) * (uint32_t)(NB * NR) + nb_b + (uint32_t)n;
      sh_eta[NXT][n] = NOISE_STD_F * jax_normal(idx);
    }
  } else if (tid >= 448 && tid < 448 + NI) {
    if (PF) {
      int j = tid - 448;
      sh_x[NXT][j] = (CUR == 0) ? xnA : xnB;
      int tf = t + 3;
      if (tf > TSTEPS - 1) tf = TSTEPS - 1;
      float xl = xb[tf * NI + j];
      if (CUR == 0) xnA = xl; else xnB = xl;
    }
  }
  wg_barrier_lds();
}

__global__ __launch_bounds__(512, 2)
void rnn_fallback(const float* __restrict__ x,
                  const float* __restrict__ h0,
                  const float* __restrict__ Winp,
                  const float* __restrict__ Wrec,
                  const float* __restrict__ brec,
                  float* __restrict__ out) {
  const int b   = blockIdx.x;
  const int tid = threadIdx.x;
  __shared__ float sh_h[NR];
  __shared__ float sh_part[10 * NR];
  __shared__ float sh_x[2][16];
  __shared__ float sh_eta[2][NR];
  const int  k_th = tid / 50;
  const int  r_th = tid % 50;
  const bool mac_active = (tid < 500);
  float w[4][20];
  if (mac_active) {
#pragma unroll
    for (int j = 0; j < 4; ++j) {
      const float* wr = Wrec + (size_t)(4 * r_th + j) * NR + 20 * k_th;
#pragma unroll
      for (int q = 0; q < 5; ++q) {
        float4 v = *(const float4*)(wr + 4 * q);
        w[j][4 * q + 0] = v.x; w[j][4 * q + 1] = v.y;
        w[j][4 * q + 2] = v.z; w[j][4 * q + 3] = v.w;
      }
    }
  }
  float winp[NI];
  float brec_r = 0.0f, h_reg = 0.0f;
  float* obp = nullptr;
  const float* xb = x + (size_t)b * TSTEPS * NI;
  float* ob       = out + (size_t)b * TSTEPS * NR;
  if (tid < NR) {
#pragma unroll
    for (int i = 0; i < NI; ++i) winp[i] = Winp[tid * NI + i];
    brec_r = brec[tid];
    h_reg  = h0[(size_t)b * NR + tid];
    sh_h[tid] = h_reg;
    obp = ob + tid;
  }
  const uint32_t nb_b = (uint32_t)b * (uint32_t)NR;
  float xnA = 0.0f, xnB = 0.0f;
  if ((tid >= 256 && tid < 448) || (tid >= 200 && tid < 208)) {
    int n = (tid >= 256) ? (tid - 256) : (tid - 8);
    sh_eta[0][n] = NOISE_STD_F * jax_normal(nb_b + (uint32_t)n);
  }
  if (tid >= 448 && tid < 448 + NI) {
    int j = tid - 448;
    sh_x[0][j] = xb[j];
    xnA = xb[NI + j];
    xnB = xb[2 * NI + j];
  }
  __syncthreads();
  const float* hp      = sh_h + 20 * k_th;
  float*       part_wp = sh_part + k_th * NR + 4 * r_th;
  for (int t = 0; t < TSTEPS - 2; t += 2) {
    fb_step<0, true>(t,     tid, mac_active, w, winp, brec_r, h_reg, obp,
                     xnA, xnB, xb, nb_b, hp, part_wp, sh_h, sh_part, sh_x, sh_eta);
    fb_step<1, true>(t + 1, tid, mac_active, w, winp, brec_r, h_reg, obp,
                     xnA, xnB, xb, nb_b, hp, part_wp, sh_h, sh_part, sh_x, sh_eta);
  }
  fb_step<0, true >(TSTEPS - 2, tid, mac_active, w, winp, brec_r, h_reg, obp,
                    xnA, xnB, xb, nb_b, hp, part_wp, sh_h, sh_part, sh_x, sh_eta);
  fb_step<1, false>(TSTEPS - 1, tid, mac_active, w, winp, brec_r, h_reg, obp,
                    xnA, xnB, xb, nb_b, hp, part_wp, sh_h, sh_part, sh_x, sh_eta);
}

extern "C" void kernel_launch(void* const* d_in, const int* in_sizes, int n_in,
                              void* d_out, int out_size, void* d_ws, size_t ws_size,
                              hipStream_t stream) {
  const float* x    = (const float*)d_in[0];  // [256,1000,10]
  const float* h0   = (const float*)d_in[1];  // [256,200]
  const float* Winp = (const float*)d_in[2];  // [200,10]
  const float* Wrec = (const float*)d_in[3];  // [200,200]
  const float* brec = (const float*)d_in[4];  // [200]
  float* out = (float*)d_out;                 // [256,1000,200]
  (void)in_sizes; (void)n_in; (void)out_size;

  const size_t eta_bytes = ETA_FLOATS * sizeof(float);  // 204.8 MB
  if (d_ws != nullptr && ws_size >= eta_bytes) {
    noise_fill<<<dim3(4096), dim3(256), 0, stream>>>((float*)d_ws);
    rnn_rowreg<<<dim3(NB), dim3(256), 0, stream>>>(
        x, h0, Winp, Wrec, brec, (const float*)d_ws, out);
  } else {
    rnn_fallback<<<dim3(NB), dim3(512), 0, stream>>>(
        x, h0, Winp, Wrec, brec, out);
  }
}

// Round 6
// 1010.269 us; speedup vs baseline: 1.7408x; 1.4068x over previous
//
#include <hip/hip_runtime.h>
#include <cstdint>
#include <cstddef>

#define TSTEPS 1000
#define NB     256
#define NR     200
#define NI     10
#define ALPHA_F     0.1f
#define NOISE_STD_F 0.01f
#define ETA_STRIDE  (NB * NR)          // 51200 floats per timestep
#define ETA_FLOATS  ((size_t)TSTEPS * NB * NR)

// ---------------- JAX threefry2x32-20, key = (0, 42) --------------------
__device__ __forceinline__ uint32_t rotl32(uint32_t v, uint32_t d) {
  return (v << d) | (v >> (32u - d));
}

__device__ __forceinline__ uint32_t threefry_bits(uint32_t c1) {
  const uint32_t ks0 = 0u;
  const uint32_t ks1 = 42u;
  const uint32_t ks2 = 0x1BD11BDAu ^ ks0 ^ ks1;
  uint32_t x0 = ks0;
  uint32_t x1 = c1 + ks1;
#define TFR(r) { x0 += x1; x1 = rotl32(x1, (r)); x1 ^= x0; }
  TFR(13) TFR(15) TFR(26) TFR(6)   x0 += ks1; x1 += ks2 + 1u;
  TFR(17) TFR(29) TFR(16) TFR(24)  x0 += ks2; x1 += ks0 + 2u;
  TFR(13) TFR(15) TFR(26) TFR(6)   x0 += ks0; x1 += ks1 + 3u;
  TFR(17) TFR(29) TFR(16) TFR(24)  x0 += ks1; x1 += ks2 + 4u;
  TFR(13) TFR(15) TFR(26) TFR(6)   x0 += ks2; x1 += ks0 + 5u;
#undef TFR
  return x0 ^ x1;
}

// XLA ErfInv32 (Giles).
__device__ __forceinline__ float erfinv_f32(float x) {
  float w = -__logf(fmaf(-x, x, 1.0f));
  float p;
  if (w < 5.0f) {
    w = w - 2.5f;
    p = 2.81022636e-08f;
    p = fmaf(p, w, 3.43273939e-07f);
    p = fmaf(p, w, -3.5233877e-06f);
    p = fmaf(p, w, -4.39150654e-06f);
    p = fmaf(p, w, 0.00021858087f);
    p = fmaf(p, w, -0.00125372503f);
    p = fmaf(p, w, -0.00417768164f);
    p = fmaf(p, w, 0.246640727f);
    p = fmaf(p, w, 1.50140941f);
  } else {
    w = sqrtf(w) - 3.0f;
    p = -0.000200214257f;
    p = fmaf(p, w, 0.000100950558f);
    p = fmaf(p, w, 0.00134934322f);
    p = fmaf(p, w, -0.00367342844f);
    p = fmaf(p, w, 0.00573950773f);
    p = fmaf(p, w, -0.0076224613f);
    p = fmaf(p, w, 0.00943887047f);
    p = fmaf(p, w, 1.00167406f);
    p = fmaf(p, w, 2.83297682f);
  }
  return p * x;
}

__device__ __forceinline__ float jax_normal(uint32_t idx) {
  uint32_t bits = threefry_bits(idx);
  float f = __uint_as_float((bits >> 9) | 0x3F800000u) - 1.0f;  // [0,1)
  const float lo = -0.99999994f;                                 // nextafter(-1,0)
  float u = fmaf(f, 2.0f, lo);
  u = fmaxf(lo, u);
  return 1.41421356f * erfinv_f32(u);
}

// exp-based tanh: ~2ulp. tanh(y)=sign(y)*(1-t)/(1+t), t=exp(-2|y|).
__device__ __forceinline__ float tanh_fast(float y) {
  float ay = fabsf(y);
  float t  = __expf(-2.0f * ay);
  float r  = (1.0f - t) * __frcp_rn(1.0f + t);
  return copysignf(r, y);
}

// LDS-only barrier: orders DS ops without draining vmcnt (keeps global
// out-stores and eta/x pipeline loads in flight).
__device__ __forceinline__ void wg_barrier_lds() {
  asm volatile("s_waitcnt lgkmcnt(0)\n\ts_barrier" ::: "memory");
}

// ---------------- dense noise pre-generation (map kernel) ----------------
__launch_bounds__(256)
__global__ void noise_fill(float* __restrict__ ws) {
  const int64_t nq = (int64_t)ETA_FLOATS / 4;          // float4 groups
  const int64_t stride = (int64_t)gridDim.x * blockDim.x;
  for (int64_t i = (int64_t)blockIdx.x * blockDim.x + threadIdx.x;
       i < nq; i += stride) {
    uint32_t base = (uint32_t)(i * 4);
    float4 v;
    v.x = NOISE_STD_F * jax_normal(base + 0u);
    v.y = NOISE_STD_F * jax_normal(base + 1u);
    v.z = NOISE_STD_F * jax_normal(base + 2u);
    v.w = NOISE_STD_F * jax_normal(base + 3u);
    ((float4*)ws)[i] = v;
  }
}

// ============ R=8 split-role kernel: MAC waves 0-3, UPD waves 4-7 ========
// 512 threads. MAC: tid<250 -> k_th=tid/25 in [0,10), r_th=tid%25 owns
//   rows 8r..8r+7 x k-chunk [20k,20k+20). w = 40 NAMED float4 (160 regs;
//   launch_bounds(512,1) -> 256-VGPR cap so it can stay resident).
//   Per step: 5 ds_read_b128 of sh_h, 160 fmaf (same 20-chunk order as the
//   verified kernel -> bit-identical), 2 ds_write_b128 partials.
// UPD: waves 4-7 lanes<50 -> row=(wv-4)*50+ln. Reads 10 partials
//   (stride-208 from a per-row base), x-drive, tanh, Euler, h/out stores.
//   eta: per-lane REGISTER pipeline from the pre-generated workspace
//   (1 coalesced b32 global load per step, 2-step slack; no LDS eta).
// x: wave4 lanes 50-54 float2 LDS pipeline (2-step slack).
// Partial layout [k][2][104]: quad lo (rows 8r..8r+3) at 208k+4r, quad hi
//   at +104 -> writer ~3-way bank spread, reader base is q-independent.

#define DECLW8(r) float4 W##r##_0, W##r##_1, W##r##_2, W##r##_3, W##r##_4;

#define LOADW8(r) {                                                         \
  const float* wp_ = Wrec + (size_t)(8 * r_th + (r)) * NR + 20 * k_th;      \
  W##r##_0 = *(const float4*)(wp_);                                         \
  W##r##_1 = *(const float4*)(wp_ + 4);                                     \
  W##r##_2 = *(const float4*)(wp_ + 8);                                     \
  W##r##_3 = *(const float4*)(wp_ + 12);                                    \
  W##r##_4 = *(const float4*)(wp_ + 16); }

// 20 sequential fmafs from 0.0f: exactly the verified per-chunk order.
#define ROWACC(r)                                                           \
  float a##r = 0.0f;                                                        \
  a##r = fmaf(W##r##_0.x, h0_.x, a##r);                                     \
  a##r = fmaf(W##r##_0.y, h0_.y, a##r);                                     \
  a##r = fmaf(W##r##_0.z, h0_.z, a##r);                                     \
  a##r = fmaf(W##r##_0.w, h0_.w, a##r);                                     \
  a##r = fmaf(W##r##_1.x, h1_.x, a##r);                                     \
  a##r = fmaf(W##r##_1.y, h1_.y, a##r);                                     \
  a##r = fmaf(W##r##_1.z, h1_.z, a##r);                                     \
  a##r = fmaf(W##r##_1.w, h1_.w, a##r);                                     \
  a##r = fmaf(W##r##_2.x, h2_.x, a##r);                                     \
  a##r = fmaf(W##r##_2.y, h2_.y, a##r);                                     \
  a##r = fmaf(W##r##_2.z, h2_.z, a##r);                                     \
  a##r = fmaf(W##r##_2.w, h2_.w, a##r);                                     \
  a##r = fmaf(W##r##_3.x, h3_.x, a##r);                                     \
  a##r = fmaf(W##r##_3.y, h3_.y, a##r);                                     \
  a##r = fmaf(W##r##_3.z, h3_.z, a##r);                                     \
  a##r = fmaf(W##r##_3.w, h3_.w, a##r);                                     \
  a##r = fmaf(W##r##_4.x, h4_.x, a##r);                                     \
  a##r = fmaf(W##r##_4.y, h4_.y, a##r);                                     \
  a##r = fmaf(W##r##_4.z, h4_.z, a##r);                                     \
  a##r = fmaf(W##r##_4.w, h4_.w, a##r);

// One step. CURI: literal 0/1 (x double-buffer + eta reg select). TT: t.
#define STEP(CURI, TT) {                                                    \
  /* ---------- phase A: MAC (waves 0-3) ---------- */                      \
  if (mac_active) {                                                         \
    float4 h0_ = *(const float4*)(hb);                                      \
    float4 h1_ = *(const float4*)(hb + 4);                                  \
    float4 h2_ = *(const float4*)(hb + 8);                                  \
    float4 h3_ = *(const float4*)(hb + 12);                                 \
    float4 h4_ = *(const float4*)(hb + 16);                                 \
    ROWACC(0) ROWACC(1) ROWACC(2) ROWACC(3)                                 \
    ROWACC(4) ROWACC(5) ROWACC(6) ROWACC(7)                                 \
    *(float4*)pw0 = make_float4(a0, a1, a2, a3);                            \
    *(float4*)pw1 = make_float4(a4, a5, a6, a7);                            \
  }                                                                         \
  wg_barrier_lds();                                                         \
  /* ---------- phase B: UPD (waves 4-7) ---------- */                      \
  if (upd_active) {                                                         \
    float y = brec_r;                                                       \
    y += pr[0 * 208];                                                       \
    y += pr[1 * 208];                                                       \
    y += pr[2 * 208];                                                       \
    y += pr[3 * 208];                                                       \
    y += pr[4 * 208];                                                       \
    y += pr[5 * 208];                                                       \
    y += pr[6 * 208];                                                       \
    y += pr[7 * 208];                                                       \
    y += pr[8 * 208];                                                       \
    y += pr[9 * 208];                                                       \
    float4 xv0 = *(const float4*)(&sh_x[CURI][0]);                          \
    float4 xv1 = *(const float4*)(&sh_x[CURI][4]);                          \
    float2 xv2 = *(const float2*)(&sh_x[CURI][8]);                          \
    y = fmaf(winp[0], xv0.x, y);                                            \
    y = fmaf(winp[1], xv0.y, y);                                            \
    y = fmaf(winp[2], xv0.z, y);                                            \
    y = fmaf(winp[3], xv0.w, y);                                            \
    y = fmaf(winp[4], xv1.x, y);                                            \
    y = fmaf(winp[5], xv1.y, y);                                            \
    y = fmaf(winp[6], xv1.z, y);                                            \
    y = fmaf(winp[7], xv1.w, y);                                            \
    y = fmaf(winp[8], xv2.x, y);                                            \
    y = fmaf(winp[9], xv2.y, y);                                            \
    float rate = tanh_fast(y);                                              \
    float eta  = (CURI == 0) ? etaA : etaB;                                 \
    float hn = h_reg + ALPHA_F * (((-h_reg) + rate) + eta);                 \
    h_reg = hn;                                                             \
    sh_h[urow] = hn;                                                        \
    *obp = hn;                                                              \
    obp += NR;                                                              \
    int tf_ = (TT) + 2;                                                     \
    if (tf_ > TSTEPS - 1) tf_ = TSTEPS - 1;  /* harmless redundant load */  \
    float e_ = etab[(size_t)tf_ * ETA_STRIDE + urow];                       \
    if (CURI == 0) etaA = e_; else etaB = e_;                               \
  } else if (xpipe) {                                                       \
    *(float2*)(&sh_x[(CURI) ^ 1][2 * xj]) = (CURI == 0) ? xnA : xnB;        \
    int tf_ = (TT) + 3;                                                     \
    if (tf_ > TSTEPS - 1) tf_ = TSTEPS - 1;                                 \
    float2 x_ = *(const float2*)(xb + tf_ * NI + 2 * xj);                   \
    if (CURI == 0) xnA = x_; else xnB = x_;                                 \
  }                                                                         \
  wg_barrier_lds(); }

__launch_bounds__(512, 1)
__global__ void rnn_r8(const float* __restrict__ x,
                       const float* __restrict__ h0,
                       const float* __restrict__ Winp,
                       const float* __restrict__ Wrec,
                       const float* __restrict__ brec,
                       const float* __restrict__ eta_ws,
                       float* __restrict__ out) {
  const int b   = blockIdx.x;
  const int tid = threadIdx.x;
  const int wv  = tid >> 6;
  const int ln  = tid & 63;

  __shared__ float sh_h[NR];           // hidden state (single buffer)
  __shared__ float sh_part[10 * 208];  // partials [k][2][104], quad-split
  __shared__ float sh_x[2][16];        // x_t double buffer

  const bool mac_active = (tid < 250);
  const int  k_th = tid / 25;          // [0,10) when mac_active
  const int  r_th = tid % 25;          // [0,25)

  const bool upd_active = (wv >= 4) && (ln < 50);
  const int  urow = (wv - 4) * 50 + ln;           // valid iff upd_active
  const bool xpipe = (wv == 4) && (ln >= 50) && (ln < 55);
  const int  xj    = ln - 50;

  const float* xb   = x + (size_t)b * TSTEPS * NI;
  const float* etab = eta_ws + (size_t)b * NR;
  float* ob         = out + (size_t)b * TSTEPS * NR;

  // --- MAC-thread stationary weights: 40 named float4 (160 regs) ---
  DECLW8(0) DECLW8(1) DECLW8(2) DECLW8(3)
  DECLW8(4) DECLW8(5) DECLW8(6) DECLW8(7)
  const float* hb = nullptr;   // per-thread h chunk base
  float* pw0 = nullptr;        // partial write ptrs (quad lo / hi)
  float* pw1 = nullptr;

  // --- UPD-thread state ---
  float winp[NI];
  float brec_r = 0.0f;
  float h_reg  = 0.0f;
  float etaA = 0.0f, etaB = 0.0f;
  float* obp = nullptr;
  const float* pr = nullptr;   // partial read base (q-independent)
  float2 xnA = make_float2(0.f, 0.f);
  float2 xnB = make_float2(0.f, 0.f);

  if (mac_active) {
    LOADW8(0) LOADW8(1) LOADW8(2) LOADW8(3)
    LOADW8(4) LOADW8(5) LOADW8(6) LOADW8(7)
    hb  = sh_h + 20 * k_th;
    pw0 = sh_part + 208 * k_th + 4 * r_th;
    pw1 = pw0 + 104;
  } else if (upd_active) {
#pragma unroll
    for (int i = 0; i < NI; ++i) winp[i] = Winp[urow * NI + i];
    brec_r = brec[urow];
    h_reg  = h0[(size_t)b * NR + urow];
    sh_h[urow] = h_reg;
    obp = ob + urow;
    // partial base: row urow = 8r+j -> 4r + (j&3) + 104*(j>=4)
    pr = sh_part + 4 * (urow >> 3) + (urow & 3) + ((urow & 7) >= 4 ? 104 : 0);
    etaA = etab[urow];                                   // eta(0)
    etaB = etab[(size_t)1 * ETA_STRIDE + urow];          // eta(1)
  } else if (xpipe) {
    *(float2*)(&sh_x[0][2 * xj]) = *(const float2*)(xb + 2 * xj);  // x(0)
    xnA = *(const float2*)(xb + NI + 2 * xj);                      // x(1)
    xnB = *(const float2*)(xb + 2 * NI + 2 * xj);                  // x(2)
  }
  __syncthreads();

  // main loop: unroll x2, compile-time CUR; all tails clamped (no peel)
  for (int t = 0; t < TSTEPS; t += 2) {
    STEP(0, t)
    STEP(1, t + 1)
  }
}

// ================== fallback: verified R1-style kernel ===================
// (in-kernel noise; used only if workspace is unavailable — 898 us rocprof.)
template <int CUR, bool PF>
__device__ __forceinline__ void fb_step(
    int t, int tid, bool mac_active,
    const float (&w)[4][20], const float (&winp)[NI], float brec_r,
    float& h_reg, float*& obp, float& xnA, float& xnB,
    const float* __restrict__ xb, uint32_t nb_b,
    const float* __restrict__ hp, float* __restrict__ part_wp,
    float* __restrict__ sh_h, float* __restrict__ sh_part,
    float (*__restrict__ sh_x)[16], float (*__restrict__ sh_eta)[NR]) {
  constexpr int NXT = CUR ^ 1;
  if (mac_active) {
    float a0 = 0.0f, a1 = 0.0f, a2 = 0.0f, a3 = 0.0f;
#pragma unroll
    for (int q = 0; q < 5; ++q) {
      float4 hv = *(const float4*)(hp + 4 * q);
      a0 = fmaf(w[0][4 * q + 0], hv.x, a0);
      a1 = fmaf(w[1][4 * q + 0], hv.x, a1);
      a2 = fmaf(w[2][4 * q + 0], hv.x, a2);
      a3 = fmaf(w[3][4 * q + 0], hv.x, a3);
      a0 = fmaf(w[0][4 * q + 1], hv.y, a0);
      a1 = fmaf(w[1][4 * q + 1], hv.y, a1);
      a2 = fmaf(w[2][4 * q + 1], hv.y, a2);
      a3 = fmaf(w[3][4 * q + 1], hv.y, a3);
      a0 = fmaf(w[0][4 * q + 2], hv.z, a0);
      a1 = fmaf(w[1][4 * q + 2], hv.z, a1);
      a2 = fmaf(w[2][4 * q + 2], hv.z, a2);
      a3 = fmaf(w[3][4 * q + 2], hv.z, a3);
      a0 = fmaf(w[0][4 * q + 3], hv.w, a0);
      a1 = fmaf(w[1][4 * q + 3], hv.w, a1);
      a2 = fmaf(w[2][4 * q + 3], hv.w, a2);
      a3 = fmaf(w[3][4 * q + 3], hv.w, a3);
    }
    *(float4*)part_wp = make_float4(a0, a1, a2, a3);
  }
  wg_barrier_lds();
  if (tid < NR) {
    float y = brec_r;
#pragma unroll
    for (int q = 0; q < 10; ++q) y += sh_part[q * NR + tid];
    float4 xv0 = *(const float4*)(&sh_x[CUR][0]);
    float4 xv1 = *(const float4*)(&sh_x[CUR][4]);
    float2 xv2 = *(const float2*)(&sh_x[CUR][8]);
    y = fmaf(winp[0], xv0.x, y);
    y = fmaf(winp[1], xv0.y, y);
    y = fmaf(winp[2], xv0.z, y);
    y = fmaf(winp[3], xv0.w, y);
    y = fmaf(winp[4], xv1.x, y);
    y = fmaf(winp[5], xv1.y, y);
    y = fmaf(winp[6], xv1.z, y);
    y = fmaf(winp[7], xv1.w, y);
    y = fmaf(winp[8], xv2.x, y);
    y = fmaf(winp[9], xv2.y, y);
    float rate = tanh_fast(y);
    float eta  = sh_eta[CUR][tid];
    float hn = h_reg + ALPHA_F * (((-h_reg) + rate) + eta);
    h_reg = hn;
    sh_h[tid] = hn;
    *obp = hn;
    obp += NR;
  } else if ((tid >= 256 && tid < 448) || (tid < 208)) {
    if (PF) {
      int n = (tid >= 256) ? (tid - 256) : (tid - 8);
      uint32_t idx = (uint32_t)(t + 1) * (uint32_t)(NB * NR) + nb_b + (uint32_t)n;
      sh_eta[NXT][n] = NOISE_STD_F * jax_normal(idx);
    }
  } else if (tid >= 448 && tid < 448 + NI) {
    if (PF) {
      int j = tid - 448;
      sh_x[NXT][j] = (CUR == 0) ? xnA : xnB;
      int tf = t + 3;
      if (tf > TSTEPS - 1) tf = TSTEPS - 1;
      float xl = xb[tf * NI + j];
      if (CUR == 0) xnA = xl; else xnB = xl;
    }
  }
  wg_barrier_lds();
}

__global__ __launch_bounds__(512, 2)
void rnn_fallback(const float* __restrict__ x,
                  const float* __restrict__ h0,
                  const float* __restrict__ Winp,
                  const float* __restrict__ Wrec,
                  const float* __restrict__ brec,
                  float* __restrict__ out) {
  const int b   = blockIdx.x;
  const int tid = threadIdx.x;
  __shared__ float sh_h[NR];
  __shared__ float sh_part[10 * NR];
  __shared__ float sh_x[2][16];
  __shared__ float sh_eta[2][NR];
  const int  k_th = tid / 50;
  const int  r_th = tid % 50;
  const bool mac_active = (tid < 500);
  float w[4][20];
  if (mac_active) {
#pragma unroll
    for (int j = 0; j < 4; ++j) {
      const float* wr = Wrec + (size_t)(4 * r_th + j) * NR + 20 * k_th;
#pragma unroll
      for (int q = 0; q < 5; ++q) {
        float4 v = *(const float4*)(wr + 4 * q);
        w[j][4 * q + 0] = v.x; w[j][4 * q + 1] = v.y;
        w[j][4 * q + 2] = v.z; w[j][4 * q + 3] = v.w;
      }
    }
  }
  float winp[NI];
  float brec_r = 0.0f, h_reg = 0.0f;
  float* obp = nullptr;
  const float* xb = x + (size_t)b * TSTEPS * NI;
  float* ob       = out + (size_t)b * TSTEPS * NR;
  if (tid < NR) {
#pragma unroll
    for (int i = 0; i < NI; ++i) winp[i] = Winp[tid * NI + i];
    brec_r = brec[tid];
    h_reg  = h0[(size_t)b * NR + tid];
    sh_h[tid] = h_reg;
    obp = ob + tid;
  }
  const uint32_t nb_b = (uint32_t)b * (uint32_t)NR;
  float xnA = 0.0f, xnB = 0.0f;
  if ((tid >= 256 && tid < 448) || (tid >= 200 && tid < 208)) {
    int n = (tid >= 256) ? (tid - 256) : (tid - 8);
    sh_eta[0][n] = NOISE_STD_F * jax_normal(nb_b + (uint32_t)n);
  }
  if (tid >= 448 && tid < 448 + NI) {
    int j = tid - 448;
    sh_x[0][j] = xb[j];
    xnA = xb[NI + j];
    xnB = xb[2 * NI + j];
  }
  __syncthreads();
  const float* hp      = sh_h + 20 * k_th;
  float*       part_wp = sh_part + k_th * NR + 4 * r_th;
  for (int t = 0; t < TSTEPS - 2; t += 2) {
    fb_step<0, true>(t,     tid, mac_active, w, winp, brec_r, h_reg, obp,
                     xnA, xnB, xb, nb_b, hp, part_wp, sh_h, sh_part, sh_x, sh_eta);
    fb_step<1, true>(t + 1, tid, mac_active, w, winp, brec_r, h_reg, obp,
                     xnA, xnB, xb, nb_b, hp, part_wp, sh_h, sh_part, sh_x, sh_eta);
  }
  fb_step<0, true >(TSTEPS - 2, tid, mac_active, w, winp, brec_r, h_reg, obp,
                    xnA, xnB, xb, nb_b, hp, part_wp, sh_h, sh_part, sh_x, sh_eta);
  fb_step<1, false>(TSTEPS - 1, tid, mac_active, w, winp, brec_r, h_reg, obp,
                    xnA, xnB, xb, nb_b, hp, part_wp, sh_h, sh_part, sh_x, sh_eta);
}

extern "C" void kernel_launch(void* const* d_in, const int* in_sizes, int n_in,
                              void* d_out, int out_size, void* d_ws, size_t ws_size,
                              hipStream_t stream) {
  const float* x    = (const float*)d_in[0];  // [256,1000,10]
  const float* h0   = (const float*)d_in[1];  // [256,200]
  const float* Winp = (const float*)d_in[2];  // [200,10]
  const float* Wrec = (const float*)d_in[3];  // [200,200]
  const float* brec = (const float*)d_in[4];  // [200]
  float* out = (float*)d_out;                 // [256,1000,200]
  (void)in_sizes; (void)n_in; (void)out_size;

  const size_t eta_bytes = ETA_FLOATS * sizeof(float);  // 204.8 MB
  if (d_ws != nullptr && ws_size >= eta_bytes) {
    noise_fill<<<dim3(4096), dim3(256), 0, stream>>>((float*)d_ws);
    rnn_r8<<<dim3(NB), dim3(512), 0, stream>>>(
        x, h0, Winp, Wrec, brec, (const float*)d_ws, out);
  } else {
    rnn_fallback<<<dim3(NB), dim3(512), 0, stream>>>(
        x, h0, Winp, Wrec, brec, out);
  }
}